// Round 10
// baseline (242.308 us; speedup 1.0000x reference)
//
#include <hip/hip_runtime.h>

#define NB 32
#define NC 511      // T-1 context positions
#define NK 8        // senses (center)
#define NS 8        // senses (context)
#define ND 300      // embedding dim
#define ND4 75      // float4 per row
#define NCH2 64     // m~ chunks per b (16 cgroups x 4 waves)
#define EPS_COS 1e-8f

// Math notes (verified R1-R6, absmax 0.0):
//  - positional log-weight is constant => center_pos/query_token_ids unused.
//  - cosine(cen,m) scale-invariant => accumulate unnormalized m~ = sum_c e^a v.
//  - R10: timed window = ~184us fixed ws-poison fills (2x ~92us), untouchable.
//  - R12/R13: 4096 concurrent wave-streams (1024 blocks) = +30us => keep 2048.
//  - R14 (233.8, prior best): LDS dbuf, 1 barrier/group: k_vam 45us = 3.5TB/s.
//  - R15 post-mortem (239.6): depth-2 prefetch ~270 VGPR live -> spill.
//    Pattern across R10/R12/R15: widening the in-flight window via registers
//    always hits the VGPR budget.
//  - R16 (resubmitted; prior attempt never ran - broker timeout): remove the
//    barriers instead. Per-wave m~ accumulation: no LDS, no __syncthreads in
//    the streaming kernel. Wave owns 8 CONSECUTIVE c's; per c: 16 NT loads ->
//    mean -> dots (cen L1-reloaded, clobber stops hoist) -> butterfly -> exp
//    -> broadcast -> FMA into macc[8] (64 VGPR). Decoupled waves each keep 16
//    loads outstanding while waiting -> per-CU in-flight stays high with NO
//    pipeline regs (~165 VGPR total). part: 64 chunks/b. Differs from R10's
//    failed register fusion: no cen hoist (clobber), 0 LDS, ~165 VGPR.

typedef float nfloat4 __attribute__((ext_vector_type(4)));

__device__ __forceinline__ void n4add(nfloat4& a, const nfloat4& b) { a += b; }

// ---------------------------------------------------------------------------
// K1: block = (b, cg); wave w owns c in [cg*32 + w*8, +8) (consecutive ->
// contiguous 76.8KB stream per wave). Barrier-free: all data stays in-wave.
// ---------------------------------------------------------------------------
__global__ __launch_bounds__(256, 2) void k_vam(const float* __restrict__ ctx,
                                                const float* __restrict__ cen,
                                                float* __restrict__ part) {
    const int b    = blockIdx.x >> 4;        // 16 cgroups per b
    const int cg   = blockIdx.x & 15;
    const int w    = threadIdx.x >> 6;       // 4 waves
    const int lane = threadIdx.x & 63;
    const int i0 = lane;
    const int i1 = lane + 64;
    const bool has1 = (i1 < ND4);            // lanes 0..10 own a second float4

    const nfloat4* cen4 = (const nfloat4*)cen + (size_t)b * NK * ND4;

    nfloat4 macc0[NK] = {};                  // m~ partial, d = 4*i0..4*i0+3
    nfloat4 macc1[NK] = {};                  // m~ partial, d = 4*i1.. (lanes<11)

    const int c0 = cg * 32 + w * 8;

#pragma unroll 1
    for (int ci = 0; ci < 8; ++ci) {
        const int c = c0 + ci;
        if (c >= NC) break;                  // only cg=15,w=3 last iter

        const nfloat4* ctx4 =
            (const nfloat4*)ctx + (size_t)(b * NC + c) * NS * ND4;

        // ---- batched NT loads: 8 unmasked + one exec-toggle block of 8 ----
        nfloat4 X[NS];
#pragma unroll
        for (int s = 0; s < NS; ++s)
            X[s] = __builtin_nontemporal_load(&ctx4[s * ND4 + i0]);
        nfloat4 Y[NS] = {};                  // stays 0 for lanes >= 11
        if (has1) {
#pragma unroll
            for (int s = 0; s < NS; ++s)
                Y[s] = __builtin_nontemporal_load(&ctx4[s * ND4 + i1]);
        }

        // ---- tree mean over senses ----
        n4add(X[0], X[1]); n4add(X[2], X[3]); n4add(X[4], X[5]); n4add(X[6], X[7]);
        n4add(X[0], X[2]); n4add(X[4], X[6]);
        n4add(X[0], X[4]);
        n4add(Y[0], Y[1]); n4add(Y[2], Y[3]); n4add(Y[4], Y[5]); n4add(Y[6], Y[7]);
        n4add(Y[0], Y[2]); n4add(Y[4], Y[6]);
        n4add(Y[0], Y[4]);
        const float inv = 0.125f;            // 1/S
        nfloat4 s0 = X[0] * inv;
        nfloat4 s1 = Y[0] * inv;             // zero beyond lane 10

        // ---- 8 dots vs cen (L1-resident; reloaded per c, clobber below) ----
        float pk[NK];
#pragma unroll
        for (int k = 0; k < NK; ++k) {
            nfloat4 ca = cen4[k * ND4 + i0];
            float p = ca.x * s0.x + ca.y * s0.y + ca.z * s0.z + ca.w * s0.w;
            if (has1) {
                nfloat4 cb = cen4[k * ND4 + i1];
                p += cb.x * s1.x + cb.y * s1.y + cb.z * s1.z + cb.w * s1.w;
            }
            pk[k] = p;
        }

        // ---- distributed exchange-butterfly: lane l -> total for k = l&7 ----
        const bool b0 = (lane & 1) != 0;
        float r[4];
#pragma unroll
        for (int j = 0; j < 4; ++j) {
            float keep = b0 ? pk[2 * j + 1] : pk[2 * j];
            float send = b0 ? pk[2 * j]     : pk[2 * j + 1];
            r[j] = keep + __shfl_xor(send, 1);
        }
        const bool b1 = (lane & 2) != 0;
        float q0, q1;
        { float keep = b1 ? r[1] : r[0]; float send = b1 ? r[0] : r[1];
          q0 = keep + __shfl_xor(send, 2); }
        { float keep = b1 ? r[3] : r[2]; float send = b1 ? r[2] : r[3];
          q1 = keep + __shfl_xor(send, 2); }
        const bool b2 = (lane & 4) != 0;
        float u;
        { float keep = b2 ? q1 : q0; float send = b2 ? q0 : q1;
          u = keep + __shfl_xor(send, 4); }
        u += __shfl_xor(u, 8);
        u += __shfl_xor(u, 16);
        u += __shfl_xor(u, 32);

        const float scale = 0.057735026919f; // 1/sqrt(300)
        float e = __expf(u * scale);         // lane l holds ea for k=l&7

        // ---- broadcast ea[0..7] from lanes 0..7, FMA into macc ----
        float eav[NK];
#pragma unroll
        for (int k = 0; k < NK; ++k) eav[k] = __shfl(e, k);
#pragma unroll
        for (int k = 0; k < NK; ++k) {
            macc0[k] += eav[k] * s0;
            macc1[k] += eav[k] * s1;         // 0 for lanes >= 11: harmless
        }

        // keep cen fragments / addresses from being hoisted across c's
        asm volatile("" ::: "memory");
    }

    // ---- per-wave coalesced part write: chunk = cg*4 + w ----
    const int chunk = cg * 4 + w;
#pragma unroll
    for (int k = 0; k < NK; ++k) {
        nfloat4* pp = (nfloat4*)(part +
            (((size_t)(b * NK + k)) * NCH2 + chunk) * ND);   // 1200B rows, 16B aligned
        pp[i0] = macc0[k];
        if (has1) pp[i1] = macc1[k];
    }
}

// ---------------------------------------------------------------------------
// K2: per b — wave w owns k=w: sum the 64 m~ chunk-partials along d (contiguous
// [NCH2][ND] panel per (b,k)), cosine vs cen row, then softmax/argmax/pooled.
// ---------------------------------------------------------------------------
__global__ __launch_bounds__(512) void k_fin2(const float* __restrict__ part,
                                              const float* __restrict__ cen,
                                              float* __restrict__ out) {
    const int b    = blockIdx.x;
    const int w    = threadIdx.x >> 6;       // = k
    const int lane = threadIdx.x & 63;
    __shared__ float sred[NK];
    __shared__ int bidx;

    const float* pp = part + ((size_t)b * NK + w) * NCH2 * ND;
    const float* cp = cen + (size_t)(b * NK + w) * ND;
    float num = 0.f, n1 = 0.f, n2 = 0.f;
    for (int d = lane; d < ND; d += 64) {
        float mval = 0.f;
#pragma unroll
        for (int ch = 0; ch < NCH2; ++ch) mval += pp[ch * ND + d];
        float cv = cp[d];
        num += cv * mval; n1 += cv * cv; n2 += mval * mval;
    }
#pragma unroll
    for (int off = 32; off; off >>= 1) {
        num += __shfl_down(num, off);
        n1  += __shfl_down(n1, off);
        n2  += __shfl_down(n2, off);
    }
    if (lane == 0) {
        float denom = fmaxf(sqrtf(n1), EPS_COS) * fmaxf(sqrtf(n2), EPS_COS);
        sred[w] = num / denom;
    }
    __syncthreads();

    if (threadIdx.x == 0) {
        float mx = sred[0];
#pragma unroll
        for (int k = 1; k < NK; ++k) mx = fmaxf(mx, sred[k]);
        float e[NK], sum = 0.f;
#pragma unroll
        for (int k = 0; k < NK; ++k) { e[k] = __expf(sred[k] - mx); sum += e[k]; }
        float invs = 1.f / sum;
        int best = 0; float bv = sred[0];
#pragma unroll
        for (int k = 1; k < NK; ++k) if (sred[k] > bv) { bv = sred[k]; best = k; }
#pragma unroll
        for (int k = 0; k < NK; ++k)
            out[(size_t)NB * ND + b * NK + k] = e[k] * invs;
        bidx = best;
    }
    __syncthreads();

    const float* src = cen + (size_t)(b * NK + bidx) * ND;
    for (int idx = threadIdx.x; idx < ND; idx += 512)
        out[(size_t)b * ND + idx] = src[idx];
}

extern "C" void kernel_launch(void* const* d_in, const int* in_sizes, int n_in,
                              void* d_out, int out_size, void* d_ws, size_t ws_size,
                              hipStream_t stream) {
    // d_in[0]=center_pos, d_in[1]=query_token_ids: unused (log-weight constant)
    const float* cen = (const float*)d_in[2];   // [B,K,d]
    const float* ctx = (const float*)d_in[3];   // [B,C,S,d]
    float* out = (float*)d_out;                 // pooled [B,d] then q [B,K]

    float* part = (float*)d_ws;                 // [B][K][NCH2][ND] = 19.7 MB

    k_vam<<<dim3(NB * 16), dim3(256), 0, stream>>>(ctx, cen, part);
    k_fin2<<<dim3(NB), dim3(512), 0, stream>>>(part, cen, out);
}